// Round 10
// baseline (1993.377 us; speedup 1.0000x reference)
//
#include <hip/hip_runtime.h>

// Problem constants (match reference)
constexpr int NB   = 8;     // batches
constexpr int NC   = 64;    // channels
constexpr int NN   = 8192;  // points
constexpr int NM   = 2048;  // samples
constexpr int NK   = 16;    // knn
constexpr int NFPS = 1433;  // int(2048*0.7)
constexpr int NRAND = NM - NFPS; // 615

// ---------------- workspace layout (bytes) ----------------
// control plane (zeroed every launch): [0] worker-barrier ctr,
// [64..95] fpsProg[8], [128..191] permFlag[16]
constexpr size_t OFF_CTR   = 0;
constexpr size_t OFF_IDX   = 256;      // int idx[8][2048]
constexpr size_t OFF_V1    = 66048;    // uint v1[8][8192]
constexpr size_t OFF_XT    = 1377280;  // float xT[8][8192][64]

typedef float v2f __attribute__((ext_vector_type(2)));

struct TF { unsigned a, b; };

__device__ __forceinline__ TF tf2(unsigned k0, unsigned k1, unsigned c0, unsigned c1) {
  unsigned ks2 = k0 ^ k1 ^ 0x1BD11BDAu;
  unsigned x0 = c0 + k0;
  unsigned x1 = c1 + k1;
#define TF_R(r) { x0 += x1; x1 = (x1 << r) | (x1 >> (32 - r)); x1 ^= x0; }
  TF_R(13) TF_R(15) TF_R(26) TF_R(6)
  x0 += k1;  x1 += ks2 + 1u;
  TF_R(17) TF_R(29) TF_R(16) TF_R(24)
  x0 += ks2; x1 += k0 + 2u;
  TF_R(13) TF_R(15) TF_R(26) TF_R(6)
  x0 += k0;  x1 += k1 + 3u;
  TF_R(17) TF_R(29) TF_R(16) TF_R(24)
  x0 += k1;  x1 += ks2 + 4u;
  TF_R(13) TF_R(15) TF_R(26) TF_R(6)
  x0 += ks2; x1 += k0 + 5u;
#undef TF_R
  TF r; r.a = x0; r.b = x1; return r;
}

// DPP-based wave64 max (VALU latency, no LDS on the chain).
__device__ __forceinline__ float wave_max_dpp(float v) {
  int vi;
  vi = __builtin_amdgcn_update_dpp(__float_as_int(v), __float_as_int(v), 0x111, 0xf, 0xf, false);
  v = fmaxf(v, __int_as_float(vi));
  vi = __builtin_amdgcn_update_dpp(__float_as_int(v), __float_as_int(v), 0x112, 0xf, 0xf, false);
  v = fmaxf(v, __int_as_float(vi));
  vi = __builtin_amdgcn_update_dpp(__float_as_int(v), __float_as_int(v), 0x114, 0xf, 0xf, false);
  v = fmaxf(v, __int_as_float(vi));
  vi = __builtin_amdgcn_update_dpp(__float_as_int(v), __float_as_int(v), 0x118, 0xf, 0xf, false);
  v = fmaxf(v, __int_as_float(vi));
  vi = __builtin_amdgcn_update_dpp(__float_as_int(v), __float_as_int(v), 0x142, 0xa, 0xf, false);
  v = fmaxf(v, __int_as_float(vi));
  vi = __builtin_amdgcn_update_dpp(__float_as_int(v), __float_as_int(v), 0x143, 0xc, 0xf, false);
  v = fmaxf(v, __int_as_float(vi));
  return __int_as_float(__builtin_amdgcn_readlane(__float_as_int(v), 63));
}

// cold poll on a dedicated control line; data itself is read ONCE afterwards
__device__ __forceinline__ void poll_ge(unsigned* p, unsigned target) {
  while (__hip_atomic_load(p, __ATOMIC_RELAXED, __HIP_MEMORY_SCOPE_AGENT) < target)
    __builtin_amdgcn_s_sleep(32);   // ~2048 cycles between polls
}
__device__ __forceinline__ int load_i(int* p) {
  return __hip_atomic_load(p, __ATOMIC_RELAXED, __HIP_MEMORY_SCOPE_AGENT);
}
__device__ __forceinline__ unsigned load_u(unsigned* p) {
  return __hip_atomic_load(p, __ATOMIC_RELAXED, __HIP_MEMORY_SCOPE_AGENT);
}

constexpr int FPS_BLKS = NB;          // 8 fps blocks
constexpr int NW = 256 - FPS_BLKS;    // 248 worker blocks
constexpr int TR_TILES = (NN / 32) * (NC / 32) * NB;  // 4096
constexpr int KNN_GRPS = NB * NM / 4;                  // 4096 groups of 4 samples

// ---------------- mega kernel: everything in ONE co-resident launch ----------
// Blocks 0-7: fps (R8 math; atomic idx publish + per-32-iter progress counter).
// Blocks 8-255: transpose -> fence+counter barrier -> perm (workers 0-15,
// atomic stores + done flag) -> knn+final per sample (poll PROGRESS counters,
// never the data lines; single atomic data load when ready) -> possub.
// DAG acyclic; producers never wait -> all polls terminate.
__global__ __launch_bounds__(256, 1) void mega_kernel(const float* __restrict__ pos,
                                                      const float* __restrict__ x,
                                                      int* __restrict__ idx,
                                                      unsigned* __restrict__ v1buf,
                                                      float* __restrict__ xT,
                                                      float* __restrict__ xOut,
                                                      float* __restrict__ posOut,
                                                      unsigned* __restrict__ ctrl) {
  __shared__ __align__(16) char smem[98432];
  const int bid = blockIdx.x;
  const int tid = threadIdx.x;
  unsigned* wbar    = ctrl;            // worker barrier counter
  unsigned* fpsProg = ctrl + 16;       // [8]  per-batch fps progress
  unsigned* permFlg = ctrl + 32;       // [16] per (b,r) perm done flags

  if (bid < FPS_BLKS) {
    // ================= FPS (256 thr, 4 waves; R8-exact math) ===================
    float* ldsX = (float*)smem;                       // 32 KB
    float* ldsY = (float*)(smem + 32768);             // 32 KB
    float* ldsZ = (float*)(smem + 65536);             // 32 KB
    float2 (*slot)[4] = (float2(*)[4])(smem + 98304); // [2][4]
    const int b = bid;
    const int wv = tid >> 6, lane = tid & 63;
    const float* pb = pos + (size_t)b * 3 * NN;
    v2f px[16], py[16], pz[16], dist[16];   // 32 points as 16 pairs
    const int base = tid * 32;   // tid-major ownership => lane order == index order
    const float4* fx = (const float4*)(pb + base);
    const float4* fy = (const float4*)(pb + NN + base);
    const float4* fz = (const float4*)(pb + 2 * NN + base);
#pragma unroll
    for (int q = 0; q < 8; ++q) {
      float4 a = fx[q], c = fy[q], e = fz[q];
      px[2*q].x = a.x; px[2*q].y = a.y; px[2*q+1].x = a.z; px[2*q+1].y = a.w;
      py[2*q].x = c.x; py[2*q].y = c.y; py[2*q+1].x = c.z; py[2*q+1].y = c.w;
      pz[2*q].x = e.x; pz[2*q].y = e.y; pz[2*q+1].x = e.z; pz[2*q+1].y = e.w;
      ((float4*)(ldsX + base))[q] = a;   // one-time stage
      ((float4*)(ldsY + base))[q] = c;
      ((float4*)(ldsZ + base))[q] = e;
    }
#pragma unroll
    for (int p = 0; p < 16; ++p) { dist[p].x = 1e10f; dist[p].y = 1e10f; }
    // inline start index: jax.random.key(42) -> keys[b] -> randint
    TF kb_ = tf2(0u, 42u, 0u, (unsigned)b);
    TF k2 = tf2(kb_.a, kb_.b, 0u, 1u);
    TF bt = tf2(k2.a, k2.b, 0u, 0u);
    int widx = (int)((bt.a ^ bt.b) & (unsigned)(NN - 1));
    if (tid == 0) {
      __hip_atomic_store(&idx[b * NM], widx, __ATOMIC_RELAXED, __HIP_MEMORY_SCOPE_AGENT);
      __hip_atomic_store(&fpsProg[b], 1u, __ATOMIC_RELEASE, __HIP_MEMORY_SCOPE_AGENT);
    }
    __syncthreads();
    float cx = ldsX[widx], cy = ldsY[widx], cz = ldsZ[widx];
    for (int it = 1; it < NFPS; ++it) {
      const int par = it & 1;
      float bestv = -1.0f; int bestS = 0;
      {
        v2f cx2; cx2.x = cx; cx2.y = cx;
        v2f cy2; cy2.x = cy; cy2.y = cy;
        v2f cz2; cz2.x = cz; cz2.y = cz;
#pragma unroll
        for (int p = 0; p < 16; ++p) {
          // Mirror numpy/XLA exactly per half: rn ops, NO fma contraction,
          // ((dx2+dy2)+dz2). contract(off) keeps pk_mul/pk_add separate.
#pragma clang fp contract(off)
          v2f dx = px[p] - cx2;
          v2f dy = py[p] - cy2;
          v2f dz = pz[p] - cz2;
          v2f d2 = (dx * dx + dy * dy) + dz * dz;
          float nd0 = fminf(dist[p].x, d2.x);
          float nd1 = fminf(dist[p].y, d2.y);
          dist[p].x = nd0; dist[p].y = nd1;
          // per-slot tracking, ascending slot order (2p, 2p+1), strict >
          bool c0 = nd0 > bestv;
          bestv = c0 ? nd0 : bestv;
          bestS = c0 ? 2*p : bestS;
          bool c1 = nd1 > bestv;
          bestv = c1 ? nd1 : bestv;
          bestS = c1 ? 2*p + 1 : bestS;
        }
      }
      const int gidx = base + bestS;
      const float wm = wave_max_dpp(bestv);
      unsigned long long msk = __ballot(bestv == wm);  // nonzero: max lane matches
      const int fl = (int)__builtin_ctzll(msk);        // lowest lane = smallest index
      const int widxw = __builtin_amdgcn_readlane(gidx, fl);
      if (lane == 0) slot[par][wv] = make_float2(wm, __int_as_float(widxw));
      __syncthreads();
      float2 s0 = slot[par][0], s1 = slot[par][1], s2 = slot[par][2], s3 = slot[par][3];
      if (s1.x > s0.x) s0 = s1;     // ties keep lower wave = smaller index
      if (s3.x > s2.x) s2 = s3;
      if (s2.x > s0.x) s0 = s2;
      widx = __float_as_int(s0.y);
      cx = ldsX[widx]; cy = ldsY[widx]; cz = ldsZ[widx];  // uniform broadcast reads
      if (tid == 0) {
        __hip_atomic_store(&idx[b * NM + it], widx, __ATOMIC_RELAXED, __HIP_MEMORY_SCOPE_AGENT);
        // progress on a DEDICATED control line, 1 release store / 32 iters:
        // consumers poll THIS, never the idx lines -> no frontier ping-pong
        if ((it & 31) == 31)
          __hip_atomic_store(&fpsProg[b], (unsigned)(it + 1), __ATOMIC_RELEASE,
                             __HIP_MEMORY_SCOPE_AGENT);
      }
    }
    if (tid == 0)
      __hip_atomic_store(&fpsProg[b], (unsigned)NFPS, __ATOMIC_RELEASE,
                         __HIP_MEMORY_SCOPE_AGENT);
    return;
  }

  // ======================= worker blocks =====================================
  const int w = bid - FPS_BLKS;   // 0..247

  // ---- phase 1: transpose x [B,C,N] -> xT [B,N,C], grid-stride over tiles ----
  {
    float (*t)[33] = (float(*)[33])smem;
    const int tx = tid & 31, ty0 = tid >> 5;  // 32 x 8
    for (int tt = w; tt < TR_TILES; tt += NW) {
      const int n0 = (tt & 255) * 32;
      const int c0 = ((tt >> 8) & 1) * 32;
      const int bb = tt >> 9;
#pragma unroll
      for (int r = 0; r < 4; ++r) {
        const int ty = ty0 + r * 8;
        t[ty][tx] = x[((size_t)bb * NC + (c0 + ty)) * NN + n0 + tx];
      }
      __syncthreads();
#pragma unroll
      for (int r = 0; r < 4; ++r) {
        const int ty = ty0 + r * 8;
        xT[((size_t)bb * NN + (n0 + ty)) * NC + c0 + tx] = t[tx][ty];
      }
      __syncthreads();
    }
  }
  // ---- worker barrier: xT must be globally visible before final reads it ----
  __threadfence();            // release: flush this CU's xT stores
  __syncthreads();
  if (tid == 0) {
    atomicAdd(wbar, 1u);
    while (__hip_atomic_load(wbar, __ATOMIC_RELAXED, __HIP_MEMORY_SCOPE_AGENT) < (unsigned)NW)
      __builtin_amdgcn_s_sleep(8);
  }
  __syncthreads();
  __threadfence();            // acquire: no stale xT lines before first read

  // ---- phase 2: permutation sorts (workers 0-15; atomic-store outputs) ------
  if (w < 16) {
    unsigned long long* s = (unsigned long long*)smem; // 64 KB
    const int b = w >> 1, r = w & 1;
    TF keyr = tf2(0u, 42u, 0u, 1u);
    TF rk = tf2(keyr.a, keyr.b, 0u, (unsigned)b);
    TF s1k = tf2(rk.a, rk.b, 0u, 1u);                // round-1 subkey
    TF nk  = tf2(rk.a, rk.b, 0u, 0u);                // round-1 carried key
    TF s2k = tf2(nk.a, nk.b, 0u, 1u);                // round-2 subkey
    const unsigned ka = r ? s2k.a : s1k.a;
    const unsigned kb = r ? s2k.b : s1k.b;
    for (int i = tid; i < NN; i += 256) {
      TF t = tf2(ka, kb, 0u, (unsigned)i);
      // composite (key<<32)|position => stable sort incl. key collisions
      s[i] = ((unsigned long long)(t.a ^ t.b) << 32) | (unsigned)i;
    }
    for (unsigned k = 2; k <= 8192u; k <<= 1) {
      for (unsigned j = k >> 1; j > 0; j >>= 1) {
        __syncthreads();
        for (unsigned t2 = (unsigned)tid; t2 < 4096u; t2 += 256u) {
          unsigned i = ((t2 & ~(j - 1u)) << 1) | (t2 & (j - 1u));
          unsigned p = i | j;
          bool up = ((i & k) == 0u);
          unsigned long long a = s[i], c = s[p];
          if ((a > c) == up) { s[i] = c; s[p] = a; }
        }
      }
    }
    __syncthreads();
    if (r == 0) {
      unsigned* v1 = v1buf + (size_t)b * NN;
      for (int i = tid; i < NN; i += 256)
        __hip_atomic_store(&v1[i], (unsigned)(s[i] & 0xffffffffu),
                           __ATOMIC_RELAXED, __HIP_MEMORY_SCOPE_AGENT);
    } else {
      for (int t2 = tid; t2 < NRAND; t2 += 256)
        __hip_atomic_store(&idx[b * NM + NFPS + t2], (int)(s[t2] & 0xffffffffu),
                           __ATOMIC_RELAXED, __HIP_MEMORY_SCOPE_AGENT);
    }
    // all block stores are at the coherent point (vmcnt drained per wave at the
    // barrier below is not needed: atomic stores complete before flag release
    // because tid0's release orders ITS view after the __syncthreads drain)
    __syncthreads();
    if (tid == 0)
      __hip_atomic_store(&permFlg[w], 1u, __ATOMIC_RELEASE, __HIP_MEMORY_SCOPE_AGENT);
  }
  __syncthreads();   // LDS handoff perm -> knn

  // ---- phase 3: knn+final per sample group (4 samples/block-step) -----------
  {
    unsigned long long (*lst)[NK][64] = (unsigned long long(*)[NK][64])smem; // 32 KB
    float (*tile)[4] = (float(*)[4])(smem + 32768);                          // [64][4]
    const int wv = tid >> 6, lane = tid & 63;
    for (int g4 = w; g4 < KNN_GRPS; g4 += NW) {
      const int g = g4 * 4 + wv;
      const int b = g >> 11, mm = g & (NM - 1);
      const float* pb = pos + (size_t)b * 3 * NN;
      int raw;
      int id;
      if (mm < NFPS) {
        poll_ge(&fpsProg[b], (unsigned)(mm + 1));     // cold control-line poll
        raw = load_i(&idx[b * NM + mm]);
        id = raw;
      } else {
        poll_ge(&permFlg[b * 2 + 1], 1u);             // rand idx ready
        raw = load_i(&idx[b * NM + mm]);
        poll_ge(&permFlg[b * 2 + 0], 1u);             // v1 ready
        id = (int)load_u(&v1buf[(size_t)b * NN + raw]);
      }
      const float sx = pb[id], sy = pb[NN + id], sz = pb[2 * NN + id];
      const float sm = __fadd_rn(__fadd_rn(__fmul_rn(sx, sx), __fmul_rn(sy, sy)),
                                 __fmul_rn(sz, sz));
      float key[NK]; int kid[NK];
#pragma unroll
      for (int i = 0; i < NK; ++i) { key[i] = __int_as_float(0x7F800000); kid[i] = 0; }
      for (int t = 0; t < NN / 256; ++t) {
        const int n0 = t * 256 + lane * 4;
        const float4 xv = *(const float4*)(pb + n0);
        const float4 yv = *(const float4*)(pb + NN + n0);
        const float4 zv = *(const float4*)(pb + 2 * NN + n0);
#pragma unroll
        for (int j = 0; j < 4; ++j) {
          const float xx = (j == 0) ? xv.x : (j == 1) ? xv.y : (j == 2) ? xv.z : xv.w;
          const float yy = (j == 0) ? yv.x : (j == 1) ? yv.y : (j == 2) ? yv.z : yv.w;
          const float zz = (j == 0) ? zv.x : (j == 1) ? zv.y : (j == 2) ? zv.z : zv.w;
          float sn = __fadd_rn(__fadd_rn(__fmul_rn(xx, xx), __fmul_rn(yy, yy)), __fmul_rn(zz, zz));
          float dt = __fadd_rn(__fadd_rn(__fmul_rn(sx, xx), __fmul_rn(sy, yy)), __fmul_rn(sz, zz));
          float d2 = __fsub_rn(__fadd_rn(sm, sn), __fmul_rn(2.0f, dt)); // mirror reference
          const float ck = d2; const int ci = n0 + j;
          // branchless sorted insert; unique composites make merge order exact
#pragma unroll
          for (int i = NK - 1; i >= 1; --i) {
            float lo = key[i-1], hi = key[i];
            bool cLo = ck < lo, cHi = ck < hi;
            key[i] = __builtin_amdgcn_fmed3f(ck, lo, hi);
            kid[i] = cLo ? kid[i-1] : (cHi ? ci : kid[i]);
          }
          bool c0 = ck < key[0];
          kid[0] = c0 ? ci : kid[0];
          key[0] = fminf(key[0], ck);
        }
      }
      // dump sorted lists (order-flipped keys); same-wave access, no barrier
#pragma unroll
      for (int i = 0; i < NK; ++i) {
        unsigned u = __float_as_uint(key[i]);
        u = (u & 0x80000000u) ? ~u : (u | 0x80000000u);
        lst[wv][i][lane] = ((unsigned long long)u << 32) | (unsigned)kid[i];
      }
      // merge 64 sorted lists: 16 rounds of wave-min; unique composites
      int ptr = 0;
      unsigned long long head = lst[wv][0][lane];
      unsigned myn = 0;
      for (int k = 0; k < NK; ++k) {
        unsigned long long mn = head;
#pragma unroll
        for (int off = 32; off > 0; off >>= 1) {
          unsigned long long o = __shfl_xor(mn, off, 64);
          if (o < mn) mn = o;
        }
        if (head == mn) { ++ptr; head = (ptr < NK) ? lst[wv][ptr][lane] : ~0ull; }
        if (lane == k) myn = (unsigned)(mn & 0xffffffffu);
      }
      // final for this sample, in-wave (verbatim arithmetic)
      const int kk = lane & 15;
      const int nk = (int)__shfl(myn, kk, 64);
      float dx = __fsub_rn(pb[nk], sx);
      float dy = __fsub_rn(pb[NN + nk], sy);
      float dz = __fsub_rn(pb[2 * NN + nk], sz);
      float dd = __fadd_rn(__fadd_rn(__fmul_rn(dx, dx), __fmul_rn(dy, dy)),
                           __fmul_rn(dz, dz));
      float d = __fsqrt_rn(dd);
      d = fmaxf(d, 1e-6f);
      float e = __fdiv_rn(0.0f - d, 0.2f);
      float mx = e;
#pragma unroll
      for (int off = 8; off > 0; off >>= 1) mx = fmaxf(mx, __shfl_xor(mx, off, 16));
      float ex = expf(__fsub_rn(e, mx));
      float sum = ex;
#pragma unroll
      for (int off = 8; off > 0; off >>= 1) sum = __fadd_rn(sum, __shfl_xor(sum, off, 16));
      float wgt = __fdiv_rn(ex, sum);
      float acc = 0.0f;
#pragma unroll
      for (int k = 0; k < NK; ++k) {
        float wk = __shfl(wgt, k, 64);
        int   nn = __shfl(nk, k, 64);
        acc = __fadd_rn(acc, __fmul_rn(wk, xT[((size_t)b * NN + nn) * NC + lane]));
      }
      tile[lane][wv] = acc;   // lane = channel
      __syncthreads();
      const int m0 = (g4 * 4) & (NM - 1);
      const int bb = (g4 * 4) >> 11;
      {
        int c = tid >> 2, ml = tid & 3;
        xOut[((size_t)bb * NC + c) * NM + m0 + ml] = tile[c][ml];
      }
      __syncthreads();        // tile reuse next group
    }
  }

  // ---- phase 4: possub (all flags set by now; polls fall straight through) ---
  for (int i = w * 256 + tid; i < NB * 3 * NM; i += NW * 256) {
    int mm = i & (NM - 1);
    int bd = i >> 11;            // b*3 + d
    int d = bd % 3, b = bd / 3;
    if (mm < NFPS) poll_ge(&fpsProg[b], (unsigned)(mm + 1));
    else { poll_ge(&permFlg[b * 2 + 1], 1u); poll_ge(&permFlg[b * 2 + 0], 1u); }
    int raw = load_i(&idx[b * NM + mm]);
    int id = (mm < NFPS) ? raw : (int)load_u(&v1buf[(size_t)b * NN + raw]);
    posOut[i] = pos[((size_t)b * 3 + d) * NN + id];
  }
}

extern "C" void kernel_launch(void* const* d_in, const int* in_sizes, int n_in,
                              void* d_out, int out_size, void* d_ws, size_t ws_size,
                              hipStream_t stream) {
  const float* x   = (const float*)d_in[0];
  const float* pos = (const float*)d_in[1];
  float* xOut   = (float*)d_out;
  float* posOut = xOut + (size_t)NB * NC * NM;

  char* w = (char*)d_ws;
  unsigned* ctrl = (unsigned*)(w + OFF_CTR);
  int*      idx  = (int*)(w + OFF_IDX);
  unsigned* v1   = (unsigned*)(w + OFF_V1);
  float*    xT   = (float*)(w + OFF_XT);

  // re-arm control plane EVERY launch (graph-capture safe, stream-ordered)
  hipMemsetAsync(w + OFF_CTR, 0, 256, stream);

  void* args[] = {(void*)&pos, (void*)&x, (void*)&idx, (void*)&v1,
                  (void*)&xT, (void*)&xOut, (void*)&posOut, (void*)&ctrl};
  hipError_t e = hipLaunchCooperativeKernel((const void*)mega_kernel, dim3(256), dim3(256),
                                            args, 0, stream);
  if (e != hipSuccess) {
    // fallback: normal launch — 256 blocks at 1 block/CU on 256 CUs are
    // co-resident by construction, so the producer/consumer DAG still works.
    hipLaunchKernelGGL(mega_kernel, dim3(256), dim3(256), 0, stream,
                       pos, x, idx, v1, xT, xOut, posOut, ctrl);
  }
}

// Round 11
// 1343.844 us; speedup vs baseline: 1.4833x; 1.4833x over previous
//
#include <hip/hip_runtime.h>

// Problem constants (match reference)
constexpr int NB   = 8;     // batches
constexpr int NC   = 64;    // channels
constexpr int NN   = 8192;  // points
constexpr int NM   = 2048;  // samples
constexpr int NK   = 16;    // knn
constexpr int NFPS = 1433;  // int(2048*0.7)
constexpr int NRAND = NM - NFPS; // 615

// ---------------- workspace layout (bytes) ----------------
// control plane (zeroed every launch): [0] worker-barrier, [64..95] fpsProg[8],
// [128..191] permFlag[16], [192] ticket counter
constexpr size_t OFF_CTR   = 0;
constexpr size_t OFF_IDX   = 256;      // int idx[8][2048]
constexpr size_t OFF_V1    = 66048;    // uint v1[8][8192]
constexpr size_t OFF_XT    = 1377280;  // float xT[8][8192][64]

typedef float v2f __attribute__((ext_vector_type(2)));

struct TF { unsigned a, b; };

__device__ __forceinline__ TF tf2(unsigned k0, unsigned k1, unsigned c0, unsigned c1) {
  unsigned ks2 = k0 ^ k1 ^ 0x1BD11BDAu;
  unsigned x0 = c0 + k0;
  unsigned x1 = c1 + k1;
#define TF_R(r) { x0 += x1; x1 = (x1 << r) | (x1 >> (32 - r)); x1 ^= x0; }
  TF_R(13) TF_R(15) TF_R(26) TF_R(6)
  x0 += k1;  x1 += ks2 + 1u;
  TF_R(17) TF_R(29) TF_R(16) TF_R(24)
  x0 += ks2; x1 += k0 + 2u;
  TF_R(13) TF_R(15) TF_R(26) TF_R(6)
  x0 += k0;  x1 += k1 + 3u;
  TF_R(17) TF_R(29) TF_R(16) TF_R(24)
  x0 += k1;  x1 += ks2 + 4u;
  TF_R(13) TF_R(15) TF_R(26) TF_R(6)
  x0 += ks2; x1 += k0 + 5u;
#undef TF_R
  TF r; r.a = x0; r.b = x1; return r;
}

// DPP-based wave64 max (VALU latency, no LDS on the chain).
__device__ __forceinline__ float wave_max_dpp(float v) {
  int vi;
  vi = __builtin_amdgcn_update_dpp(__float_as_int(v), __float_as_int(v), 0x111, 0xf, 0xf, false);
  v = fmaxf(v, __int_as_float(vi));
  vi = __builtin_amdgcn_update_dpp(__float_as_int(v), __float_as_int(v), 0x112, 0xf, 0xf, false);
  v = fmaxf(v, __int_as_float(vi));
  vi = __builtin_amdgcn_update_dpp(__float_as_int(v), __float_as_int(v), 0x114, 0xf, 0xf, false);
  v = fmaxf(v, __int_as_float(vi));
  vi = __builtin_amdgcn_update_dpp(__float_as_int(v), __float_as_int(v), 0x118, 0xf, 0xf, false);
  v = fmaxf(v, __int_as_float(vi));
  vi = __builtin_amdgcn_update_dpp(__float_as_int(v), __float_as_int(v), 0x142, 0xa, 0xf, false);
  v = fmaxf(v, __int_as_float(vi));
  vi = __builtin_amdgcn_update_dpp(__float_as_int(v), __float_as_int(v), 0x143, 0xc, 0xf, false);
  v = fmaxf(v, __int_as_float(vi));
  return __int_as_float(__builtin_amdgcn_readlane(__float_as_int(v), 63));
}

// cold poll on a dedicated control line; data itself is read ONCE afterwards
__device__ __forceinline__ void poll_ge(unsigned* p, unsigned target) {
  while (__hip_atomic_load(p, __ATOMIC_RELAXED, __HIP_MEMORY_SCOPE_AGENT) < target)
    __builtin_amdgcn_s_sleep(32);   // ~2048 cycles between polls
}
__device__ __forceinline__ int load_i(int* p) {
  return __hip_atomic_load(p, __ATOMIC_RELAXED, __HIP_MEMORY_SCOPE_AGENT);
}
__device__ __forceinline__ unsigned load_u(unsigned* p) {
  return __hip_atomic_load(p, __ATOMIC_RELAXED, __HIP_MEMORY_SCOPE_AGENT);
}

constexpr int FPS_BLKS = NB;          // 8 fps blocks
constexpr int NW = 256 - FPS_BLKS;    // 248 worker blocks
constexpr int TR_TILES = (NN / 32) * (NC / 32) * NB;  // 4096
constexpr int KNN_GRPS = NB * NM / 4;                  // 4096 groups of 4 samples

// ---------------- mega kernel: everything in ONE co-resident launch ----------
// Blocks 0-7: fps (R10-exact). Blocks 8-255: transpose -> barrier -> perm
// (workers 0-15) -> knn+final via DYNAMIC ticket queue ordered by sample
// readiness (fix for R9/R10's static-schedule stragglers) -> possub.
__global__ __launch_bounds__(256, 1) void mega_kernel(const float* __restrict__ pos,
                                                      const float* __restrict__ x,
                                                      int* __restrict__ idx,
                                                      unsigned* __restrict__ v1buf,
                                                      float* __restrict__ xT,
                                                      float* __restrict__ xOut,
                                                      float* __restrict__ posOut,
                                                      unsigned* __restrict__ ctrl) {
  __shared__ __align__(16) char smem[98432];
  const int bid = blockIdx.x;
  const int tid = threadIdx.x;
  unsigned* wbar    = ctrl;            // worker barrier counter
  unsigned* fpsProg = ctrl + 16;       // [8]  per-batch fps progress
  unsigned* permFlg = ctrl + 32;       // [16] per (b,r) perm done flags
  unsigned* ticket  = ctrl + 48;       // global group ticket

  if (bid < FPS_BLKS) {
    // ================= FPS (256 thr, 4 waves; R10-exact) =======================
    float* ldsX = (float*)smem;                       // 32 KB
    float* ldsY = (float*)(smem + 32768);             // 32 KB
    float* ldsZ = (float*)(smem + 65536);             // 32 KB
    float2 (*slot)[4] = (float2(*)[4])(smem + 98304); // [2][4]
    const int b = bid;
    const int wv = tid >> 6, lane = tid & 63;
    const float* pb = pos + (size_t)b * 3 * NN;
    v2f px[16], py[16], pz[16], dist[16];   // 32 points as 16 pairs
    const int base = tid * 32;   // tid-major ownership => lane order == index order
    const float4* fx = (const float4*)(pb + base);
    const float4* fy = (const float4*)(pb + NN + base);
    const float4* fz = (const float4*)(pb + 2 * NN + base);
#pragma unroll
    for (int q = 0; q < 8; ++q) {
      float4 a = fx[q], c = fy[q], e = fz[q];
      px[2*q].x = a.x; px[2*q].y = a.y; px[2*q+1].x = a.z; px[2*q+1].y = a.w;
      py[2*q].x = c.x; py[2*q].y = c.y; py[2*q+1].x = c.z; py[2*q+1].y = c.w;
      pz[2*q].x = e.x; pz[2*q].y = e.y; pz[2*q+1].x = e.z; pz[2*q+1].y = e.w;
      ((float4*)(ldsX + base))[q] = a;   // one-time stage
      ((float4*)(ldsY + base))[q] = c;
      ((float4*)(ldsZ + base))[q] = e;
    }
#pragma unroll
    for (int p = 0; p < 16; ++p) { dist[p].x = 1e10f; dist[p].y = 1e10f; }
    // inline start index: jax.random.key(42) -> keys[b] -> randint
    TF kb_ = tf2(0u, 42u, 0u, (unsigned)b);
    TF k2 = tf2(kb_.a, kb_.b, 0u, 1u);
    TF bt = tf2(k2.a, k2.b, 0u, 0u);
    int widx = (int)((bt.a ^ bt.b) & (unsigned)(NN - 1));
    if (tid == 0) {
      __hip_atomic_store(&idx[b * NM], widx, __ATOMIC_RELAXED, __HIP_MEMORY_SCOPE_AGENT);
      __hip_atomic_store(&fpsProg[b], 1u, __ATOMIC_RELEASE, __HIP_MEMORY_SCOPE_AGENT);
    }
    __syncthreads();
    float cx = ldsX[widx], cy = ldsY[widx], cz = ldsZ[widx];
    for (int it = 1; it < NFPS; ++it) {
      const int par = it & 1;
      float bestv = -1.0f; int bestS = 0;
      {
        v2f cx2; cx2.x = cx; cx2.y = cx;
        v2f cy2; cy2.x = cy; cy2.y = cy;
        v2f cz2; cz2.x = cz; cz2.y = cz;
#pragma unroll
        for (int p = 0; p < 16; ++p) {
          // Mirror numpy/XLA exactly per half: rn ops, NO fma contraction,
          // ((dx2+dy2)+dz2). contract(off) keeps pk_mul/pk_add separate.
#pragma clang fp contract(off)
          v2f dx = px[p] - cx2;
          v2f dy = py[p] - cy2;
          v2f dz = pz[p] - cz2;
          v2f d2 = (dx * dx + dy * dy) + dz * dz;
          float nd0 = fminf(dist[p].x, d2.x);
          float nd1 = fminf(dist[p].y, d2.y);
          dist[p].x = nd0; dist[p].y = nd1;
          // per-slot tracking, ascending slot order (2p, 2p+1), strict >
          bool c0 = nd0 > bestv;
          bestv = c0 ? nd0 : bestv;
          bestS = c0 ? 2*p : bestS;
          bool c1 = nd1 > bestv;
          bestv = c1 ? nd1 : bestv;
          bestS = c1 ? 2*p + 1 : bestS;
        }
      }
      const int gidx = base + bestS;
      const float wm = wave_max_dpp(bestv);
      unsigned long long msk = __ballot(bestv == wm);  // nonzero: max lane matches
      const int fl = (int)__builtin_ctzll(msk);        // lowest lane = smallest index
      const int widxw = __builtin_amdgcn_readlane(gidx, fl);
      if (lane == 0) slot[par][wv] = make_float2(wm, __int_as_float(widxw));
      __syncthreads();
      float2 s0 = slot[par][0], s1 = slot[par][1], s2 = slot[par][2], s3 = slot[par][3];
      if (s1.x > s0.x) s0 = s1;     // ties keep lower wave = smaller index
      if (s3.x > s2.x) s2 = s3;
      if (s2.x > s0.x) s0 = s2;
      widx = __float_as_int(s0.y);
      cx = ldsX[widx]; cy = ldsY[widx]; cz = ldsZ[widx];  // uniform broadcast reads
      if (tid == 0) {
        __hip_atomic_store(&idx[b * NM + it], widx, __ATOMIC_RELAXED, __HIP_MEMORY_SCOPE_AGENT);
        // progress on a DEDICATED control line, 1 release store / 32 iters
        if ((it & 31) == 31)
          __hip_atomic_store(&fpsProg[b], (unsigned)(it + 1), __ATOMIC_RELEASE,
                             __HIP_MEMORY_SCOPE_AGENT);
      }
    }
    if (tid == 0)
      __hip_atomic_store(&fpsProg[b], (unsigned)NFPS, __ATOMIC_RELEASE,
                         __HIP_MEMORY_SCOPE_AGENT);
    return;
  }

  // ======================= worker blocks =====================================
  const int w = bid - FPS_BLKS;   // 0..247

  // ---- phase 1: transpose x [B,C,N] -> xT [B,N,C], grid-stride over tiles ----
  {
    float (*t)[33] = (float(*)[33])smem;
    const int tx = tid & 31, ty0 = tid >> 5;  // 32 x 8
    for (int tt = w; tt < TR_TILES; tt += NW) {
      const int n0 = (tt & 255) * 32;
      const int c0 = ((tt >> 8) & 1) * 32;
      const int bb = tt >> 9;
#pragma unroll
      for (int r = 0; r < 4; ++r) {
        const int ty = ty0 + r * 8;
        t[ty][tx] = x[((size_t)bb * NC + (c0 + ty)) * NN + n0 + tx];
      }
      __syncthreads();
#pragma unroll
      for (int r = 0; r < 4; ++r) {
        const int ty = ty0 + r * 8;
        xT[((size_t)bb * NN + (n0 + ty)) * NC + c0 + tx] = t[tx][ty];
      }
      __syncthreads();
    }
  }
  // ---- worker barrier: xT must be globally visible before final reads it ----
  __threadfence();            // release: flush this CU's xT stores
  __syncthreads();
  if (tid == 0) {
    atomicAdd(wbar, 1u);
    while (__hip_atomic_load(wbar, __ATOMIC_RELAXED, __HIP_MEMORY_SCOPE_AGENT) < (unsigned)NW)
      __builtin_amdgcn_s_sleep(8);
  }
  __syncthreads();
  __threadfence();            // acquire: no stale xT lines before first read

  // ---- phase 2: permutation sorts (workers 0-15; atomic-store outputs) ------
  if (w < 16) {
    unsigned long long* s = (unsigned long long*)smem; // 64 KB
    const int b = w >> 1, r = w & 1;
    TF keyr = tf2(0u, 42u, 0u, 1u);
    TF rk = tf2(keyr.a, keyr.b, 0u, (unsigned)b);
    TF s1k = tf2(rk.a, rk.b, 0u, 1u);                // round-1 subkey
    TF nk  = tf2(rk.a, rk.b, 0u, 0u);                // round-1 carried key
    TF s2k = tf2(nk.a, nk.b, 0u, 1u);                // round-2 subkey
    const unsigned ka = r ? s2k.a : s1k.a;
    const unsigned kb = r ? s2k.b : s1k.b;
    for (int i = tid; i < NN; i += 256) {
      TF t = tf2(ka, kb, 0u, (unsigned)i);
      // composite (key<<32)|position => stable sort incl. key collisions
      s[i] = ((unsigned long long)(t.a ^ t.b) << 32) | (unsigned)i;
    }
    for (unsigned k = 2; k <= 8192u; k <<= 1) {
      for (unsigned j = k >> 1; j > 0; j >>= 1) {
        __syncthreads();
        for (unsigned t2 = (unsigned)tid; t2 < 4096u; t2 += 256u) {
          unsigned i = ((t2 & ~(j - 1u)) << 1) | (t2 & (j - 1u));
          unsigned p = i | j;
          bool up = ((i & k) == 0u);
          unsigned long long a = s[i], c = s[p];
          if ((a > c) == up) { s[i] = c; s[p] = a; }
        }
      }
    }
    __syncthreads();
    if (r == 0) {
      unsigned* v1 = v1buf + (size_t)b * NN;
      for (int i = tid; i < NN; i += 256)
        __hip_atomic_store(&v1[i], (unsigned)(s[i] & 0xffffffffu),
                           __ATOMIC_RELAXED, __HIP_MEMORY_SCOPE_AGENT);
    } else {
      for (int t2 = tid; t2 < NRAND; t2 += 256)
        __hip_atomic_store(&idx[b * NM + NFPS + t2], (int)(s[t2] & 0xffffffffu),
                           __ATOMIC_RELAXED, __HIP_MEMORY_SCOPE_AGENT);
    }
    __syncthreads();
    if (tid == 0)
      __hip_atomic_store(&permFlg[w], 1u, __ATOMIC_RELEASE, __HIP_MEMORY_SCOPE_AGENT);
  }
  __syncthreads();   // LDS handoff perm -> knn

  // ---- phase 3: knn+final via READY-ORDERED dynamic ticket queue ------------
  // ticket t -> (b, gm): A: gm 0..126 (FPS, ready<440us), B: gm 359..511
  // (rand, ready when perm done), C: gm 127..358 (FPS, ready 440..1220us).
  // Blocks grab the next-ready group; at last-sample time the backlog is ~0.
  {
    unsigned long long (*lst)[NK][64] = (unsigned long long(*)[NK][64])smem; // 32 KB
    float (*tile)[4] = (float(*)[4])(smem + 32768);                          // [64][4]
    int* tkt = (int*)(smem + 33792);
    const int wv = tid >> 6, lane = tid & 63;
    for (;;) {
      __syncthreads();          // protect tkt/tile reuse
      if (tid == 0) *tkt = (int)atomicAdd(ticket, 1u);
      __syncthreads();
      const int t = *tkt;
      if (t >= KNN_GRPS) break;
      int b, gm;
      if (t < 1016)      { gm = t >> 3;                  b = t & 7; }
      else if (t < 2240) { gm = 359 + ((t - 1016) >> 3); b = (t - 1016) & 7; }
      else               { gm = 127 + ((t - 2240) >> 3); b = (t - 2240) & 7; }
      const int mm = gm * 4 + wv;
      const float* pb = pos + (size_t)b * 3 * NN;
      int raw, id;
      if (mm < NFPS) {
        poll_ge(&fpsProg[b], (unsigned)(mm + 1));     // cold control-line poll
        raw = load_i(&idx[b * NM + mm]);
        id = raw;
      } else {
        poll_ge(&permFlg[b * 2 + 1], 1u);             // rand idx ready
        raw = load_i(&idx[b * NM + mm]);
        poll_ge(&permFlg[b * 2 + 0], 1u);             // v1 ready
        id = (int)load_u(&v1buf[(size_t)b * NN + raw]);
      }
      const float sx = pb[id], sy = pb[NN + id], sz = pb[2 * NN + id];
      const float sm = __fadd_rn(__fadd_rn(__fmul_rn(sx, sx), __fmul_rn(sy, sy)),
                                 __fmul_rn(sz, sz));
      float key[NK]; int kid[NK];
#pragma unroll
      for (int i = 0; i < NK; ++i) { key[i] = __int_as_float(0x7F800000); kid[i] = 0; }
      for (int tt2 = 0; tt2 < NN / 256; ++tt2) {
        const int n0 = tt2 * 256 + lane * 4;
        const float4 xv = *(const float4*)(pb + n0);
        const float4 yv = *(const float4*)(pb + NN + n0);
        const float4 zv = *(const float4*)(pb + 2 * NN + n0);
#pragma unroll
        for (int j = 0; j < 4; ++j) {
          const float xx = (j == 0) ? xv.x : (j == 1) ? xv.y : (j == 2) ? xv.z : xv.w;
          const float yy = (j == 0) ? yv.x : (j == 1) ? yv.y : (j == 2) ? yv.z : yv.w;
          const float zz = (j == 0) ? zv.x : (j == 1) ? zv.y : (j == 2) ? zv.z : zv.w;
          float sn = __fadd_rn(__fadd_rn(__fmul_rn(xx, xx), __fmul_rn(yy, yy)), __fmul_rn(zz, zz));
          float dt = __fadd_rn(__fadd_rn(__fmul_rn(sx, xx), __fmul_rn(sy, yy)), __fmul_rn(sz, zz));
          float d2 = __fsub_rn(__fadd_rn(sm, sn), __fmul_rn(2.0f, dt)); // mirror reference
          const float ck = d2; const int ci = n0 + j;
          // branchless sorted insert; unique composites make merge order exact
#pragma unroll
          for (int i = NK - 1; i >= 1; --i) {
            float lo = key[i-1], hi = key[i];
            bool cLo = ck < lo, cHi = ck < hi;
            key[i] = __builtin_amdgcn_fmed3f(ck, lo, hi);
            kid[i] = cLo ? kid[i-1] : (cHi ? ci : kid[i]);
          }
          bool c0 = ck < key[0];
          kid[0] = c0 ? ci : kid[0];
          key[0] = fminf(key[0], ck);
        }
      }
      // dump sorted lists (order-flipped keys); same-wave access, no barrier
#pragma unroll
      for (int i = 0; i < NK; ++i) {
        unsigned u = __float_as_uint(key[i]);
        u = (u & 0x80000000u) ? ~u : (u | 0x80000000u);
        lst[wv][i][lane] = ((unsigned long long)u << 32) | (unsigned)kid[i];
      }
      // merge 64 sorted lists: 16 rounds of wave-min; unique composites
      int ptr = 0;
      unsigned long long head = lst[wv][0][lane];
      unsigned myn = 0;
      for (int k = 0; k < NK; ++k) {
        unsigned long long mn = head;
#pragma unroll
        for (int off = 32; off > 0; off >>= 1) {
          unsigned long long o = __shfl_xor(mn, off, 64);
          if (o < mn) mn = o;
        }
        if (head == mn) { ++ptr; head = (ptr < NK) ? lst[wv][ptr][lane] : ~0ull; }
        if (lane == k) myn = (unsigned)(mn & 0xffffffffu);
      }
      // final for this sample, in-wave (verbatim arithmetic)
      const int kk = lane & 15;
      const int nk = (int)__shfl(myn, kk, 64);
      float dx = __fsub_rn(pb[nk], sx);
      float dy = __fsub_rn(pb[NN + nk], sy);
      float dz = __fsub_rn(pb[2 * NN + nk], sz);
      float dd = __fadd_rn(__fadd_rn(__fmul_rn(dx, dx), __fmul_rn(dy, dy)),
                           __fmul_rn(dz, dz));
      float d = __fsqrt_rn(dd);
      d = fmaxf(d, 1e-6f);
      float e = __fdiv_rn(0.0f - d, 0.2f);
      float mx = e;
#pragma unroll
      for (int off = 8; off > 0; off >>= 1) mx = fmaxf(mx, __shfl_xor(mx, off, 16));
      float ex = expf(__fsub_rn(e, mx));
      float sum = ex;
#pragma unroll
      for (int off = 8; off > 0; off >>= 1) sum = __fadd_rn(sum, __shfl_xor(sum, off, 16));
      float wgt = __fdiv_rn(ex, sum);
      float acc = 0.0f;
#pragma unroll
      for (int k = 0; k < NK; ++k) {
        float wk = __shfl(wgt, k, 64);
        int   nn = __shfl(nk, k, 64);
        acc = __fadd_rn(acc, __fmul_rn(wk, xT[((size_t)b * NN + nn) * NC + lane]));
      }
      tile[lane][wv] = acc;   // lane = channel
      __syncthreads();
      {
        int c = tid >> 2, ml = tid & 3;
        xOut[((size_t)b * NC + c) * NM + gm * 4 + ml] = tile[c][ml];
      }
    }
  }

  // ---- phase 4: possub (all flags set by now; polls fall straight through) ---
  for (int i = w * 256 + tid; i < NB * 3 * NM; i += NW * 256) {
    int mm = i & (NM - 1);
    int bd = i >> 11;            // b*3 + d
    int d = bd % 3, b = bd / 3;
    if (mm < NFPS) poll_ge(&fpsProg[b], (unsigned)(mm + 1));
    else { poll_ge(&permFlg[b * 2 + 1], 1u); poll_ge(&permFlg[b * 2 + 0], 1u); }
    int raw = load_i(&idx[b * NM + mm]);
    int id = (mm < NFPS) ? raw : (int)load_u(&v1buf[(size_t)b * NN + raw]);
    posOut[i] = pos[((size_t)b * 3 + d) * NN + id];
  }
}

extern "C" void kernel_launch(void* const* d_in, const int* in_sizes, int n_in,
                              void* d_out, int out_size, void* d_ws, size_t ws_size,
                              hipStream_t stream) {
  const float* x   = (const float*)d_in[0];
  const float* pos = (const float*)d_in[1];
  float* xOut   = (float*)d_out;
  float* posOut = xOut + (size_t)NB * NC * NM;

  char* w = (char*)d_ws;
  unsigned* ctrl = (unsigned*)(w + OFF_CTR);
  int*      idx  = (int*)(w + OFF_IDX);
  unsigned* v1   = (unsigned*)(w + OFF_V1);
  float*    xT   = (float*)(w + OFF_XT);

  // re-arm control plane EVERY launch (graph-capture safe, stream-ordered)
  hipMemsetAsync(w + OFF_CTR, 0, 256, stream);

  void* args[] = {(void*)&pos, (void*)&x, (void*)&idx, (void*)&v1,
                  (void*)&xT, (void*)&xOut, (void*)&posOut, (void*)&ctrl};
  hipError_t e = hipLaunchCooperativeKernel((const void*)mega_kernel, dim3(256), dim3(256),
                                            args, 0, stream);
  if (e != hipSuccess) {
    // fallback: normal launch — 256 blocks at 1 block/CU on 256 CUs are
    // co-resident by construction, so the producer/consumer DAG still works.
    hipLaunchKernelGGL(mega_kernel, dim3(256), dim3(256), 0, stream,
                       pos, x, idx, v1, xT, xOut, posOut, ctrl);
  }
}